// Round 1
// baseline (369.647 us; speedup 1.0000x reference)
//
#include <hip/hip_runtime.h>

#define BB 8
#define LL 8192
#define DD 1024

// One block per batch. 1024 threads, 8 mask elements per thread.
// Computes exclusive prefix sums of the boundary mask, derives for every
// input position its destination slot in the partitioned order, writes the
// inverse permutation perm[b*S + dest] = src for dest < S, and writes the
// float 0/1 validity mask output.
__global__ __launch_bounds__(1024) void build_perm(
    const int* __restrict__ mask, int* __restrict__ perm,
    float* __restrict__ mask_out, int S) {
  const int b = blockIdx.x;
  const int t = threadIdx.x;          // 0..1023
  const int lane = t & 63;
  const int wave = t >> 6;            // 0..15

  __shared__ int wave_sums[16];
  __shared__ int s_total;

  const int* m = mask + (size_t)b * LL;
  const int base_i = t * 8;

  int vals[8];
  int local = 0;
#pragma unroll
  for (int k = 0; k < 8; ++k) {
    vals[k] = m[base_i + k] ? 1 : 0;
    local += vals[k];
  }

  // Wave-level inclusive scan of per-thread sums (wave = 64 lanes on CDNA).
  int incl = local;
#pragma unroll
  for (int off = 1; off < 64; off <<= 1) {
    int up = __shfl_up(incl, off, 64);
    if (lane >= off) incl += up;
  }
  if (lane == 63) wave_sums[wave] = incl;
  __syncthreads();

  // Scan the 16 wave sums in wave 0.
  if (wave == 0 && lane < 16) {
    int v = wave_sums[lane];
#pragma unroll
    for (int off = 1; off < 16; off <<= 1) {
      int up = __shfl_up(v, off, 64);
      if (lane >= off) v += up;
    }
    wave_sums[lane] = v;
    if (lane == 15) s_total = v;
  }
  __syncthreads();

  const int wave_base = (wave == 0) ? 0 : wave_sums[wave - 1];
  const int num_tokens = s_total;
  int run = wave_base + incl - local;  // exclusive count of trues before base_i

#pragma unroll
  for (int k = 0; k < 8; ++k) {
    const int i = base_i + k;
    int dest;
    if (vals[k]) {
      dest = run;            // rank among true tokens
      run += 1;
    } else {
      dest = num_tokens + (i - run);  // trues done, then falses in order
    }
    if (dest < S) perm[(size_t)b * S + dest] = i;
  }

  // Validity mask output as float 0/1.
  for (int j = t; j < S; j += 1024) {
    mask_out[(size_t)b * S + j] = (j < num_tokens) ? 1.0f : 0.0f;
  }
}

// One block per output row; 256 threads x float4 = 4096 B = one D=1024 row.
__global__ __launch_bounds__(256) void gather_rows(
    const float* __restrict__ hidden, const int* __restrict__ perm,
    float* __restrict__ out, int S) {
  const int row = blockIdx.x;          // 0 .. B*S-1
  const int b = row / S;
  const int src = perm[row];
  const float4* __restrict__ in4 =
      (const float4*)(hidden + ((size_t)b * LL + (size_t)src) * DD);
  float4* __restrict__ out4 = (float4*)(out + (size_t)row * DD);
  out4[threadIdx.x] = in4[threadIdx.x];
}

extern "C" void kernel_launch(void* const* d_in, const int* in_sizes, int n_in,
                              void* d_out, int out_size, void* d_ws, size_t ws_size,
                              hipStream_t stream) {
  const float* hidden = (const float*)d_in[0];
  const int* mask = (const int*)d_in[1];

  // out_size = B*S*D + B*S  ->  S = out_size / (B*(D+1))
  const int S = out_size / (BB * (DD + 1));

  float* out_hidden = (float*)d_out;
  float* out_mask = out_hidden + (size_t)BB * S * DD;
  int* perm = (int*)d_ws;  // B*S ints

  build_perm<<<BB, 1024, 0, stream>>>(mask, perm, out_mask, S);
  gather_rows<<<BB * S, 256, 0, stream>>>(hidden, perm, out_hidden, S);
}